// Round 1
// baseline (96.514 us; speedup 1.0000x reference)
//
#include <hip/hip_runtime.h>
#include <stdint.h>

typedef unsigned int uint32;
typedef unsigned long long u64;
typedef short bf16x8 __attribute__((ext_vector_type(8)));
typedef float f32x4 __attribute__((ext_vector_type(4)));

// fp32 -> bf16 bits, round-to-nearest-even
__device__ __forceinline__ unsigned short f2bf(float f) {
  uint32 u = __builtin_bit_cast(uint32, f);
  u += 0x7FFFu + ((u >> 16) & 1u);
  return (unsigned short)(u >> 16);
}

// ---------------------------------------------------------------------------
// K1: h = X*W  (16384x128 @ 128x64), then e_src/e_dst = h . a, store
//     hT  : bf16 [B][64][2048]  (transposed, masked)  for MFMA B-operand
//     E1  = exp(e_dst), E2 = exp(0.2 e_dst)            (per j)
//     ET  = exp(-e_src), G = exp(0.8 e_src)            (per i)
// block = 256 thr: 16 row-pairs x 16 d-groups (d = dg + 16*dd, dd=0..3)
// ---------------------------------------------------------------------------
__global__ __launch_bounds__(256) void k1_h_e(
    const float* __restrict__ X, const float* __restrict__ W,
    const float* __restrict__ A, const float* __restrict__ mask,
    unsigned short* __restrict__ hT,
    float* __restrict__ E1, float* __restrict__ E2,
    float* __restrict__ ET, float* __restrict__ G) {
  __shared__ float WT[64][132];  // [d][k], pad 132: b128 reads land 2-way (free)
  const int t = threadIdx.x;
  for (int idx = t; idx < 128 * 64; idx += 256) {
    int k = idx >> 6, d = idx & 63;
    WT[d][k] = W[idx];
  }
  __syncthreads();

  const int dg = t & 15;
  const int rp = t >> 4;
  const int gi0 = blockIdx.x * 32 + rp * 2;  // row pair

  float a1[4], a2[4];
#pragma unroll
  for (int dd = 0; dd < 4; ++dd) {
    a1[dd] = A[dg + 16 * dd];
    a2[dd] = A[64 + dg + 16 * dd];
  }

  const float4* x0 = (const float4*)(X + (size_t)gi0 * 128);
  const float4* x1 = (const float4*)(X + (size_t)(gi0 + 1) * 128);
  float h0[4] = {0.f, 0.f, 0.f, 0.f}, h1[4] = {0.f, 0.f, 0.f, 0.f};
#pragma unroll 4
  for (int kq = 0; kq < 32; ++kq) {
    const float4 xa = x0[kq], xb = x1[kq];
#pragma unroll
    for (int dd = 0; dd < 4; ++dd) {
      const float4 w4 = *(const float4*)(&WT[dg + 16 * dd][kq * 4]);
      h0[dd] += xa.x * w4.x + xa.y * w4.y + xa.z * w4.z + xa.w * w4.w;
      h1[dd] += xb.x * w4.x + xb.y * w4.y + xb.z * w4.z + xb.w * w4.w;
    }
  }

  float es0 = 0.f, ed0 = 0.f, es1 = 0.f, ed1 = 0.f;
#pragma unroll
  for (int dd = 0; dd < 4; ++dd) {
    es0 += h0[dd] * a1[dd]; ed0 += h0[dd] * a2[dd];
    es1 += h1[dd] * a1[dd]; ed1 += h1[dd] * a2[dd];
  }
#pragma unroll
  for (int m = 1; m < 16; m <<= 1) {
    es0 += __shfl_xor(es0, m, 64);
    ed0 += __shfl_xor(ed0, m, 64);
    es1 += __shfl_xor(es1, m, 64);
    ed1 += __shfl_xor(ed1, m, 64);
  }
  if (dg == 0) {
    ET[gi0] = expf(-es0);      G[gi0] = expf(0.8f * es0);
    E1[gi0] = expf(ed0);       E2[gi0] = expf(0.2f * ed0);
    ET[gi0 + 1] = expf(-es1);  G[gi0 + 1] = expf(0.8f * es1);
    E1[gi0 + 1] = expf(ed1);   E2[gi0 + 1] = expf(0.2f * ed1);
  }

  const float m0 = mask[gi0], m1 = mask[gi0 + 1];
  const int b = gi0 >> 11, i = gi0 & 2047;
#pragma unroll
  for (int dd = 0; dd < 4; ++dd) {
    const int d = dg + 16 * dd;
    const uint32 lo = f2bf(h0[dd] * m0);
    const uint32 hi = f2bf(h1[dd] * m1);
    *(uint32*)(hT + (((size_t)(b * 64 + d)) << 11) + i) = lo | (hi << 16);
  }
}

// ---------------------------------------------------------------------------
// K3 (pass A): single streaming read of adj (128MB).
//   per row i: S1 = sum_{edge,pos} E1_j ; S2 = sum_{edge,!pos} E2_j
//   P1 = 1/(S1 + S2/G), P2 = 1/(S1*G + S2)
//   bitmask words: word(jc*4+k) bit l  <->  j = jc*256 + 4l + k  (via ballot)
//   layout bitw[b][widx(0..31)][i]  -> pass-B reads contiguous in i
// ---------------------------------------------------------------------------
__global__ __launch_bounds__(256) void k3_stats(
    const int* __restrict__ adj,
    const float* __restrict__ E1, const float* __restrict__ E2,
    const float* __restrict__ ET, const float* __restrict__ G,
    u64* __restrict__ bitw, float* __restrict__ P1, float* __restrict__ P2) {
  const int w = threadIdx.x >> 6, lane = threadIdx.x & 63;
  const int gi = blockIdx.x * 4 + w;
  const int b = gi >> 11, i = gi & 2047;
  const float eti = ET[gi];
  const int4* arow = (const int4*)(adj + (size_t)gi * 2048);
  const float4* e1p = (const float4*)(E1 + b * 2048);
  const float4* e2p = (const float4*)(E2 + b * 2048);
  float s1 = 0.f, s2 = 0.f;
#pragma unroll
  for (int jc = 0; jc < 8; ++jc) {
    const int idx = jc * 64 + lane;
    const int4 av = arow[idx];
    const float4 e1 = e1p[idx];
    const float4 e2 = e2p[idx];
    const bool m0 = (av.x == 1), m1b = (av.y == 1), m2 = (av.z == 1), m3 = (av.w == 1);
    const bool q0 = (e1.x > eti), q1 = (e1.y > eti), q2 = (e1.z > eti), q3 = (e1.w > eti);
    s1 += (m0 && q0) ? e1.x : 0.f;   s2 += (m0 && !q0) ? e2.x : 0.f;
    s1 += (m1b && q1) ? e1.y : 0.f;  s2 += (m1b && !q1) ? e2.y : 0.f;
    s1 += (m2 && q2) ? e1.z : 0.f;   s2 += (m2 && !q2) ? e2.z : 0.f;
    s1 += (m3 && q3) ? e1.w : 0.f;   s2 += (m3 && !q3) ? e2.w : 0.f;
    const u64 b0 = __ballot(m0), b1 = __ballot(m1b), b2 = __ballot(m2), b3 = __ballot(m3);
    if (lane < 4) {
      const u64 v = (lane == 0) ? b0 : (lane == 1) ? b1 : (lane == 2) ? b2 : b3;
      bitw[(size_t)(b * 32 + jc * 4 + lane) * 2048 + i] = v;
    }
  }
#pragma unroll
  for (int m = 1; m < 64; m <<= 1) {
    s1 += __shfl_xor(s1, m, 64);
    s2 += __shfl_xor(s2, m, 64);
  }
  if (lane == 0) {
    const float g = G[gi];
    const bool ok = (s1 + s2) > 0.f;  // guard: row with no neighbors
    P1[gi] = ok ? 1.f / (s1 + s2 / g) : 0.f;
    P2[gi] = ok ? 1.f / (s1 * g + s2) : 0.f;
  }
}

// ---------------------------------------------------------------------------
// K4 (pass B): h'[j,d] = sum_i p[i,j] * h[i,d]   via mfma_f32_16x16x32_bf16
//   p[i,j] = bit ? (E1_j>ET_i ? P1_i*E1_j : P2_i*E2_j) : 0   (built in regs)
//   block: 4 waves, j-tile 64 (wave = 16 j x 64 d), K-split KS over i.
//   A-frag: lane j = J0+(l&15) fixed, k = (l>>4)*8+e  (same k-map as B => any
//   internal k-permutation cancels).  B-frag: ds_read_b128 from hT-staged LDS.
// ---------------------------------------------------------------------------
template <int KS>
__global__ __launch_bounds__(256, 4) void k4_agg(
    const unsigned short* __restrict__ hT, const u64* __restrict__ bitw,
    const float* __restrict__ E1, const float* __restrict__ E2,
    const float* __restrict__ ET, const float* __restrict__ P1,
    const float* __restrict__ P2, float* __restrict__ part) {
  constexpr int KRANGE = 2048 / KS;
  constexpr int NKT = KRANGE / 32;
  __shared__ unsigned short sB[64 * 40];  // [d][i] pad 40 -> b128 2-way (free)
  const int t = threadIdx.x;
  const int w = t >> 6, l = t & 63;
  const int bid = blockIdx.x;
  const int jt = bid & 31;
  const int b = (bid >> 5) & 7;
  const int ks = bid >> 8;
  const int J0 = jt * 64 + w * 16;
  const int jj = J0 + (l & 15);
  const int kg = l >> 4;

  const float rE1 = E1[b * 2048 + jj];
  const float rE2 = E2[b * 2048 + jj];
  const int widx = ((jj >> 8) << 2) + (jj & 3);
  const u64* wp = bitw + (size_t)(b * 32 + widx) * 2048;
  const int sh = (jj >> 2) & 63;
  const bool hiw = sh >= 32;
  const int shh = sh & 31;
  const float* P1b = P1 + b * 2048;
  const float* P2b = P2 + b * 2048;
  const float* ETb = ET + b * 2048;
  const unsigned short* hTb = hT + ((size_t)b << 17);

  f32x4 acc[4] = {};

  const int sd = t >> 2;
  const int sii = (t & 3) * 8;

  for (int kt = 0; kt < NKT; ++kt) {
    const int i0 = ks * KRANGE + kt * 32;
    __syncthreads();
    {  // stage H tile [64 d][32 i] bf16
      const uint4 v = *(const uint4*)(hTb + (((size_t)sd) << 11) + i0 + sii);
      *(uint4*)(&sB[sd * 40 + sii]) = v;
    }
    __syncthreads();

    const int ib = i0 + kg * 8;
    const uint32* wpu = (const uint32*)(wp + ib);  // 8 u64 = 16 dwords
    const uint4 q0 = *(const uint4*)(wpu + 0);
    const uint4 q1 = *(const uint4*)(wpu + 4);
    const uint4 q2 = *(const uint4*)(wpu + 8);
    const uint4 q3 = *(const uint4*)(wpu + 12);
    const float4 p1a = *(const float4*)(P1b + ib);
    const float4 p1c = *(const float4*)(P1b + ib + 4);
    const float4 p2a = *(const float4*)(P2b + ib);
    const float4 p2c = *(const float4*)(P2b + ib + 4);
    const float4 eta = *(const float4*)(ETb + ib);
    const float4 etc_ = *(const float4*)(ETb + ib + 4);

    auto pv = [&](uint32 lo, uint32 hi, float p1v, float p2v, float etv) -> float {
      const uint32 dw = hiw ? hi : lo;
      const float v = (rE1 > etv) ? p1v * rE1 : p2v * rE2;
      return ((dw >> shh) & 1u) ? v : 0.f;
    };
    float pe[8];
    pe[0] = pv(q0.x, q0.y, p1a.x, p2a.x, eta.x);
    pe[1] = pv(q0.z, q0.w, p1a.y, p2a.y, eta.y);
    pe[2] = pv(q1.x, q1.y, p1a.z, p2a.z, eta.z);
    pe[3] = pv(q1.z, q1.w, p1a.w, p2a.w, eta.w);
    pe[4] = pv(q2.x, q2.y, p1c.x, p2c.x, etc_.x);
    pe[5] = pv(q2.z, q2.w, p1c.y, p2c.y, etc_.y);
    pe[6] = pv(q3.x, q3.y, p1c.z, p2c.z, etc_.z);
    pe[7] = pv(q3.z, q3.w, p1c.w, p2c.w, etc_.w);

    union { uint32 u[4]; bf16x8 v; } af;
#pragma unroll
    for (int e = 0; e < 4; ++e)
      af.u[e] = (uint32)f2bf(pe[2 * e]) | ((uint32)f2bf(pe[2 * e + 1]) << 16);

#pragma unroll
    for (int dt = 0; dt < 4; ++dt) {
      const bf16x8 bv = *(const bf16x8*)(&sB[(dt * 16 + (l & 15)) * 40 + kg * 8]);
      acc[dt] = __builtin_amdgcn_mfma_f32_16x16x32_bf16(af.v, bv, acc[dt], 0, 0, 0);
    }
  }

  // C/D layout: col = lane&15 (= d offset), row = (lane>>4)*4 + reg (= j offset)
  float* pout = part + (size_t)(ks * 8 + b) * (2048 * 64);
#pragma unroll
  for (int dt = 0; dt < 4; ++dt) {
#pragma unroll
    for (int r = 0; r < 4; ++r) {
      const int j = J0 + (l >> 4) * 4 + r;
      pout[(size_t)j * 64 + dt * 16 + (l & 15)] = acc[dt][r];
    }
  }
}

// ---------------------------------------------------------------------------
// K5: reduce K-split partials + ELU
// ---------------------------------------------------------------------------
__global__ __launch_bounds__(256) void k5_elu(const float* __restrict__ part,
                                              float* __restrict__ out, int KS) {
  const int idx = blockIdx.x * 256 + threadIdx.x;  // float4 index, 262144 total
  float4 s = ((const float4*)part)[idx];
  for (int k = 1; k < KS; ++k) {
    const float4 v = ((const float4*)part)[(size_t)k * 262144 + idx];
    s.x += v.x; s.y += v.y; s.z += v.z; s.w += v.w;
  }
  float4 o;
  o.x = s.x > 0.f ? s.x : expm1f(s.x);
  o.y = s.y > 0.f ? s.y : expm1f(s.y);
  o.z = s.z > 0.f ? s.z : expm1f(s.z);
  o.w = s.w > 0.f ? s.w : expm1f(s.w);
  ((float4*)out)[idx] = o;
}

extern "C" void kernel_launch(void* const* d_in, const int* in_sizes, int n_in,
                              void* d_out, int out_size, void* d_ws, size_t ws_size,
                              hipStream_t stream) {
  const float* X = (const float*)d_in[0];     // [8,2048,128] f32
  const int* adj = (const int*)d_in[1];       // [8,2048,2048] i32
  const float* mask = (const float*)d_in[2];  // [8,2048] f32
  const float* W = (const float*)d_in[3];     // [128,64] f32
  const float* A = (const float*)d_in[4];     // [128,1] f32
  float* out = (float*)d_out;                 // [8,2048,64] f32
  char* ws = (char*)d_ws;

  unsigned short* hT = (unsigned short*)(ws);     // 2 MB
  float* E1 = (float*)(ws + 2097152);             // 64 KB each
  float* E2 = (float*)(ws + 2162688);
  float* ET = (float*)(ws + 2228224);
  float* G  = (float*)(ws + 2293760);
  float* P1 = (float*)(ws + 2359296);
  float* P2 = (float*)(ws + 2424832);
  u64* bitw = (u64*)(ws + 2490368);               // 4 MB
  const size_t base_need = 6684672;

  int KS = 1;
  if (ws_size >= base_need + 4ull * 4194304) KS = 4;
  else if (ws_size >= base_need + 2ull * 4194304) KS = 2;
  float* part = (KS == 1) ? out : (float*)(ws + base_need);

  hipLaunchKernelGGL(k1_h_e, dim3(512), dim3(256), 0, stream, X, W, A, mask, hT, E1, E2, ET, G);
  hipLaunchKernelGGL(k3_stats, dim3(4096), dim3(256), 0, stream, adj, E1, E2, ET, G, bitw, P1, P2);
  if (KS == 4)
    hipLaunchKernelGGL((k4_agg<4>), dim3(1024), dim3(256), 0, stream, hT, bitw, E1, E2, ET, P1, P2, part);
  else if (KS == 2)
    hipLaunchKernelGGL((k4_agg<2>), dim3(512), dim3(256), 0, stream, hT, bitw, E1, E2, ET, P1, P2, part);
  else
    hipLaunchKernelGGL((k4_agg<1>), dim3(256), dim3(256), 0, stream, hT, bitw, E1, E2, ET, P1, P2, part);
  hipLaunchKernelGGL(k5_elu, dim3(1024), dim3(256), 0, stream, part, out, KS);
}